// Round 8
// baseline (267.552 us; speedup 1.0000x reference)
//
#include <hip/hip_runtime.h>

using uint = unsigned int;
using ushort = unsigned short;

typedef __attribute__((ext_vector_type(8))) short bf16x8;
typedef __attribute__((ext_vector_type(4))) short bf16x4;
typedef __attribute__((ext_vector_type(4))) float f32x4;

#define ADMM_ITERS 100
#define RHO_C 1.0f
#define SIGMA_C 1e-6f

__device__ inline ushort f2bf(float f) {
  union { float f; uint u; } c; c.f = f;
  uint u = c.u;
  uint r = (u + 0x7fffu + ((u >> 16) & 1u)) >> 16;
  return (ushort)r;
}

__device__ inline void gload_lds16(const void* g, void* l) {
  __builtin_amdgcn_global_load_lds(
      (const __attribute__((address_space(1))) void*)g,
      (__attribute__((address_space(3))) void*)l, 16, 0, 0);
}

// Split 8 f32 -> hi/lo bf16x8 by TRUNCATION (hi = mantissa-masked; lo = exact
// residual, truncated). Residual error ~2^-16 relative.
__device__ inline void splitPack(const float* x, bf16x8& hi, bf16x8& lo) {
#pragma unroll
  for (int j = 0; j < 8; ++j) {
    uint b = __float_as_uint(x[j]);
    uint hb = b & 0xffff0000u;
    float lf = x[j] - __uint_as_float(hb);
    hi[j] = (short)(b >> 16);
    lo[j] = (short)(__float_as_uint(lf) >> 16);
  }
}

// 4 f32 -> two hi-pair dwords + two lo-pair dwords (truncation split, even
// element in low 16 bits). Bit-identical values to splitPack.
__device__ inline void packPairs(const f32x4& x, uint& h0, uint& h1,
                                 uint& l0, uint& l1) {
  uint b0 = __float_as_uint(x[0]), b1 = __float_as_uint(x[1]);
  uint b2 = __float_as_uint(x[2]), b3 = __float_as_uint(x[3]);
  float r0 = x[0] - __uint_as_float(b0 & 0xffff0000u);
  float r1 = x[1] - __uint_as_float(b1 & 0xffff0000u);
  float r2 = x[2] - __uint_as_float(b2 & 0xffff0000u);
  float r3 = x[3] - __uint_as_float(b3 & 0xffff0000u);
  h0 = __builtin_amdgcn_perm(b1, b0, 0x07060302u);
  h1 = __builtin_amdgcn_perm(b3, b2, 0x07060302u);
  l0 = __builtin_amdgcn_perm(__float_as_uint(r1), __float_as_uint(r0), 0x07060302u);
  l1 = __builtin_amdgcn_perm(__float_as_uint(r3), __float_as_uint(r2), 0x07060302u);
}

// Row permutation for T/T0 storage (round-8): global row n -> tile-local
// position 16t+rho with sigma_t0(4q+r)=8q+r, sigma_t1(4q+r)=8q+4+r,
// sigma_t2(rho)=32+rho. Makes the MFMA D-output register layout IDENTICAL
// to the next iteration's B-fragment layout (k=8q+j lane-local) -> the
// u-transpose costs ZERO data movement.
__device__ inline int permrow(int n) {
  if (n < 32) {
    int j = n & 7;
    return ((j >> 2) << 4) + ((n >> 3) << 2) + (j & 3);
  }
  return n;   // 32..35 real, 36..47 pad
}

// ---------------------------------------------------------------------------
// prep bodies (fused into prep_all)
// ---------------------------------------------------------------------------
__device__ void transpose_body(const float* __restrict__ in, ushort* __restrict__ out,
                               int R, int C, int Cout, int bx, int by, int tid) {
  __shared__ float t[32][33];
  const int c0 = bx * 32, r0 = by * 32;
  const int tx = tid & 31, ty = tid >> 5;
  for (int rr = ty; rr < 32; rr += 8) {
    int r = r0 + rr, c = c0 + tx;
    float v = 0.0f;
    if (r < R && c < C) v = in[(long)r * C + c];
    t[rr][tx] = v;
  }
  __syncthreads();
  for (int rr = ty; rr < 32; rr += 8) {
    int c = c0 + rr, r = r0 + tx;
    if (c < Cout && r < R) out[(long)c * R + r] = f2bf(t[tx][rr]);
  }
}

// ADMM setup -> MFMA operand form. Round-8: T/T0 rows stored PERMUTED via
// permrow(n); bounds arrays stay in original n-order (kernel indexes them
// contiguously per the sigma mapping).
__device__ void setup_body(const float* __restrict__ Aeq, const float* __restrict__ beq,
                           const float* __restrict__ A, const float* __restrict__ b,
                           const float* __restrict__ ub, const float* __restrict__ lb,
                           ushort* __restrict__ Th, ushort* __restrict__ Tl,
                           ushort* __restrict__ T0h, ushort* __restrict__ T0l,
                           float* __restrict__ blp, float* __restrict__ bup, int t) {
  __shared__ float Aug[24][48];
  __shared__ float A12[12 * 24];
  __shared__ float fac[24];
  __shared__ float Tx[24][36];
  for (int i = t; i < 48 * 64; i += 256) { Th[i] = 0; Tl[i] = 0; }
  for (int i = t; i < 48 * 32; i += 256) { T0h[i] = 0; T0l[i] = 0; }
  if (t < 96)  A12[t] = Aeq[t];
  if (t < 192) A12[96 + t] = A[t];
  __syncthreads();
  for (int idx = t; idx < 576; idx += 256) {
    int j = idx / 24, k = idx % 24;
    float s = (j == k) ? (1.0f + SIGMA_C + 2.0f * RHO_C) : 0.0f;
    for (int r = 0; r < 12; ++r) s += RHO_C * A12[r * 24 + j] * A12[r * 24 + k];
    Aug[j][k] = s;
    Aug[j][24 + k] = (j == k) ? 1.0f : 0.0f;
  }
  __syncthreads();
  for (int p = 0; p < 24; ++p) {
    float rp = 1.0f / Aug[p][p];
    if (t < 24) fac[t] = Aug[t][p];
    __syncthreads();
    if (t < 48) Aug[p][t] *= rp;
    __syncthreads();
    for (int idx = t; idx < 24 * 48; idx += 256) {
      int r = idx / 48, c = idx % 48;
      if (r != p) Aug[r][c] -= fac[r] * Aug[p][c];
    }
    __syncthreads();
  }
  auto splitStore = [](ushort* hp, ushort* lp, int i, float v) {
    ushort hs = f2bf(v);
    float hf = __uint_as_float(((uint)hs) << 16);
    ushort ls = f2bf(v - hf);
    hp[i] = hs; lp[i] = ls;
  };
  for (int idx = t; idx < 24 * 36; idx += 256) {
    int n = idx / 36, k = idx % 36;
    float v;
    if (k < 24) v = 2.0f * Aug[n][24 + k];
    else {
      v = 0.0f;
      for (int j = 0; j < 24; ++j) v += Aug[n][24 + j] * A12[(k - 24) * 24 + j];
    }
    Tx[n][k] = v;
    splitStore(Th, Tl, permrow(n) * 64 + k, v);
  }
  __syncthreads();
  for (int idx = t; idx < 12 * 36; idx += 256) {
    int m = idx / 36, k = idx % 36;
    float v = 0.0f;
    for (int j = 0; j < 24; ++j) v += A12[m * 24 + j] * Tx[j][k];
    splitStore(Th, Tl, permrow(24 + m) * 64 + k, v);
  }
  for (int idx = t; idx < 36 * 24; idx += 256) {
    int n = idx / 24, k = idx % 24;
    float v;
    if (n < 24) v = Aug[n][24 + k];
    else {
      v = 0.0f;
      for (int j = 0; j < 24; ++j) v += A12[(n - 24) * 24 + j] * Aug[j][24 + k];
    }
    splitStore(T0h, T0l, permrow(n) * 32 + k, v);
  }
  if (t < 48) {
    float lv, uv;
    if (t < 24)      { lv = lb[t]; uv = ub[t]; }
    else if (t < 28) { lv = beq[t - 24]; uv = lv; }
    else if (t < 36) { lv = -1e30f; uv = b[t - 28]; }
    else             { lv = -1e30f; uv = 1e30f; }
    blp[t] = lv; bup[t] = uv;
  }
}

// Fused prep: [0,nConv) convert | [+512) W1T | [+1024) W2T | [+32) W3T | [1) setup
__global__ void prep_all(
    const float* __restrict__ state, ushort* __restrict__ stateB, int n4,
    const float* __restrict__ W1, ushort* __restrict__ W1T,
    const float* __restrict__ W2, ushort* __restrict__ W2T,
    const float* __restrict__ W3, ushort* __restrict__ W3T,
    const float* __restrict__ Aeq, const float* __restrict__ beq,
    const float* __restrict__ A, const float* __restrict__ b,
    const float* __restrict__ ub, const float* __restrict__ lb,
    ushort* __restrict__ Th, ushort* __restrict__ Tl,
    ushort* __restrict__ T0h, ushort* __restrict__ T0l,
    float* __restrict__ blp, float* __restrict__ bup) {
  const int nConv = n4 >> 8;
  int bb = blockIdx.x;
  if (bb < nConv) {
    int i = bb * 256 + threadIdx.x;
    if (i < n4) {
      float4 v = ((const float4*)state)[i];
      uint2 p;
      p.x = (uint)f2bf(v.x) | ((uint)f2bf(v.y) << 16);
      p.y = (uint)f2bf(v.z) | ((uint)f2bf(v.w) << 16);
      ((uint2*)stateB)[i] = p;
    }
    return;
  }
  bb -= nConv;
  if (bb < 512)  { transpose_body(W1, W1T, 512, 1024, 1024, bb & 31, bb >> 5, threadIdx.x); return; }
  bb -= 512;
  if (bb < 1024) { transpose_body(W2, W2T, 1024, 1024, 1024, bb & 31, bb >> 5, threadIdx.x); return; }
  bb -= 1024;
  if (bb < 32)   { transpose_body(W3, W3T, 1024, 24, 32, 0, bb, threadIdx.x); return; }
  setup_body(Aeq, beq, A, b, ub, lb, Th, Tl, T0h, T0l, blp, bup, threadIdx.x);
}

// ---------------------------------------------------------------------------
// bf16 GEMM, C = A[M,K] * Bt[N,K]^T — m97-style staging (skinny final layer).
// ---------------------------------------------------------------------------
template<int BM, int BN, int WM, int WN, int TM, int TN, int MODE>
__global__ __launch_bounds__(256) void gemm_bt(
    const ushort* __restrict__ A, const ushort* __restrict__ Bt,
    const float* __restrict__ bias, void* __restrict__ Cout_,
    int K, int ldc, int nvalid) {
  __shared__ char lds[(BM + BN) * 64];
  char* ldsA = lds;
  char* ldsB = lds + BM * 64;

  const int tid = threadIdx.x;
  const int wave = tid >> 6;
  const int lane = tid & 63;
  const int blockM = blockIdx.y * BM;
  const int blockN = blockIdx.x * BN;
  const int wm = (wave / WN) * (TM * 16);
  const int wn = (wave % WN) * (TN * 16);

  f32x4 acc[TM][TN] = {};

  const int l15 = lane & 15;
  const int kq = lane >> 4;
  constexpr int AI = BM / 16;
  constexpr int TOT = (BM + BN) / 16;
  const int srow = lane >> 2;
  const int kb = (lane & 3) ^ ((srow >> 1) & 3);

  for (int k0 = 0; k0 < K; k0 += 32) {
    for (int inst = wave; inst < TOT; inst += 4) {
      const bool isA = inst < AI;
      const int i = isA ? inst : inst - AI;
      const ushort* gp = (isA ? A : Bt)
          + (long)((isA ? blockM : blockN) + i * 16 + srow) * K + (k0 + kb * 8);
      char* lp = (isA ? ldsA : ldsB) + i * 1024;
      gload_lds16(gp, lp);
    }
    __syncthreads();

    bf16x8 af[TM], bfr[TN];
#pragma unroll
    for (int i = 0; i < TM; ++i) {
      int r = wm + i * 16 + l15;
      int ch = kq ^ ((r >> 1) & 3);
      af[i] = *(const bf16x8*)(ldsA + r * 64 + ch * 16);
    }
#pragma unroll
    for (int j = 0; j < TN; ++j) {
      int r = wn + j * 16 + l15;
      int ch = kq ^ ((r >> 1) & 3);
      bfr[j] = *(const bf16x8*)(ldsB + r * 64 + ch * 16);
    }
#pragma unroll
    for (int i = 0; i < TM; ++i)
#pragma unroll
      for (int j = 0; j < TN; ++j)
        acc[i][j] = __builtin_amdgcn_mfma_f32_16x16x32_bf16(af[i], bfr[j], acc[i][j], 0, 0, 0);
    __syncthreads();
  }

  const int ro = lane >> 4;
#pragma unroll
  for (int i = 0; i < TM; ++i) {
#pragma unroll
    for (int j = 0; j < TN; ++j) {
      const int col = blockN + wn + j * 16 + l15;
      float bv;
      if (MODE == 0) bv = bias[col];
      else bv = (col < nvalid) ? bias[col] : 0.0f;
#pragma unroll
      for (int r = 0; r < 4; ++r) {
        const int row = blockM + wm + i * 16 + ro * 4 + r;
        float v = acc[i][j][r] + bv;
        if (MODE == 0) {
          v = fmaxf(v, 0.0f);
          ((ushort*)Cout_)[(long)row * ldc + col] = f2bf(v);
        } else {
          if (col < nvalid) ((float*)Cout_)[(long)row * ldc + col] = v;
        }
      }
    }
  }
}

// ---------------------------------------------------------------------------
// 256x256 8-phase bf16 GEMM (T1+T2+T3+T4+T5) — unchanged.
// ---------------------------------------------------------------------------
#define GEMM8P_QUAD(MI0, NJ0)                                                 \
  _Pragma("unroll") for (int mi_ = 0; mi_ < 4; ++mi_)                         \
  _Pragma("unroll") for (int nj_ = 0; nj_ < 2; ++nj_)                         \
  _Pragma("unroll") for (int kk_ = 0; kk_ < 2; ++kk_)                         \
    acc[(MI0) + mi_][(NJ0) + nj_] = __builtin_amdgcn_mfma_f32_16x16x32_bf16(  \
        aF[mi_][kk_], bF[(NJ0) + nj_][kk_], acc[(MI0) + mi_][(NJ0) + nj_],    \
        0, 0, 0);

#define GEMM8P_SYNC_PRE()                              \
  __builtin_amdgcn_s_barrier();                        \
  asm volatile("s_waitcnt lgkmcnt(0)" ::: "memory");   \
  __builtin_amdgcn_sched_barrier(0);                   \
  __builtin_amdgcn_s_setprio(1);

#define GEMM8P_SYNC_POST()                             \
  __builtin_amdgcn_s_setprio(0);                       \
  __builtin_amdgcn_s_barrier();

__global__ __launch_bounds__(512, 2) void gemm8p(
    const ushort* __restrict__ A, const ushort* __restrict__ Bt,
    const float* __restrict__ bias, ushort* __restrict__ Cout,
    int K, int ldc, int nblk_n) {
  __shared__ __align__(16) char ldsc[131072];   // [2 buf][A 32K | B 32K]

  const int nwg = gridDim.x;
  const int bid = blockIdx.x;
  const int swz = (bid & 7) * (nwg >> 3) + (bid >> 3);
  const int blockM = (swz / nblk_n) * 256;
  const int blockN = (swz % nblk_n) * 256;

  const int tid = threadIdx.x;
  const int wave = tid >> 6;
  const int lane = tid & 63;
  const int l15 = lane & 15;
  const int q = lane >> 4;
  const int wm = (wave >> 2) * 128;
  const int wn = (wave & 3) * 64;
  const int nt = K >> 6;

  f32x4 acc[8][4] = {};

  auto stage = [&](int ts, int h) {
    if (ts >= nt) return;
    char* base = ldsc + ((ts & 1) << 16) + (h << 14);
#pragma unroll
    for (int j = 0; j < 2; ++j) {
      const int idx = wave * 64 + j * 512 + lane;
      const int row = idx >> 3;
      const int cs = (idx & 7) ^ (row & 7);
      const ushort* gp =
          (h < 2 ? A + (long)(blockM + ((h & 1) << 7) + row) * K
                 : Bt + (long)(blockN + ((h & 1) << 7) + row) * K)
          + (ts << 6) + cs * 8;
      gload_lds16(gp, base + ((wave * 64 + j * 512) << 4));
    }
  };
  auto dsA = [&](int cb, int mi, int kk) {
    const int r = wm + mi * 16 + l15;
    const int cs = (kk * 4 + q) ^ (r & 7);
    return *(const bf16x8*)(ldsc + (cb << 16) + r * 128 + cs * 16);
  };
  auto dsB = [&](int cb, int nj, int kk) {
    const int r = wn + nj * 16 + l15;
    const int cs = (kk * 4 + q) ^ (r & 7);
    return *(const bf16x8*)(ldsc + (cb << 16) + 32768 + r * 128 + cs * 16);
  };

  stage(0, 0); stage(0, 1); stage(0, 2); stage(0, 3);
  stage(1, 0);
  asm volatile("s_waitcnt vmcnt(2)" ::: "memory");
  __builtin_amdgcn_s_barrier();

  bf16x8 aF[4][2], bF[4][2];
#pragma unroll 1
  for (int t = 0; t < nt; ++t) {
    const int cb = t & 1;
#pragma unroll
    for (int mi = 0; mi < 4; ++mi)
#pragma unroll
      for (int kk = 0; kk < 2; ++kk) aF[mi][kk] = dsA(cb, mi, kk);
#pragma unroll
    for (int nj = 0; nj < 2; ++nj)
#pragma unroll
      for (int kk = 0; kk < 2; ++kk) bF[nj][kk] = dsB(cb, nj, kk);
    stage(t + 1, 1);
    GEMM8P_SYNC_PRE();
    GEMM8P_QUAD(0, 0);
    GEMM8P_SYNC_POST();
#pragma unroll
    for (int nj = 2; nj < 4; ++nj)
#pragma unroll
      for (int kk = 0; kk < 2; ++kk) bF[nj][kk] = dsB(cb, nj, kk);
    stage(t + 1, 2);
    GEMM8P_SYNC_PRE();
    GEMM8P_QUAD(0, 2);
    GEMM8P_SYNC_POST();
#pragma unroll
    for (int mi = 0; mi < 4; ++mi)
#pragma unroll
      for (int kk = 0; kk < 2; ++kk) aF[mi][kk] = dsA(cb, 4 + mi, kk);
    stage(t + 1, 3);
    GEMM8P_SYNC_PRE();
    GEMM8P_QUAD(4, 2);
    GEMM8P_SYNC_POST();
    stage(t + 2, 0);
    if (t + 2 < nt) { asm volatile("s_waitcnt vmcnt(2)" ::: "memory"); }
    else            { asm volatile("s_waitcnt vmcnt(0)" ::: "memory"); }
    __builtin_amdgcn_s_barrier();
    __builtin_amdgcn_s_setprio(1);
    GEMM8P_QUAD(4, 0);
    GEMM8P_SYNC_POST();
  }

#pragma unroll
  for (int mi = 0; mi < 8; ++mi) {
#pragma unroll
    for (int nj = 0; nj < 4; ++nj) {
      const int col = blockN + wn + nj * 16 + l15;
      const float bv = bias[col];
#pragma unroll
      for (int r = 0; r < 4; ++r) {
        const int row = blockM + wm + mi * 16 + q * 4 + r;
        float v = acc[mi][nj][r] + bv;
        v = fmaxf(v, 0.0f);
        Cout[(long)row * ldc + col] = f2bf(v);
      }
    }
  }
}

// ---------------------------------------------------------------------------
// ADMM via MFMA (round-8: permuted-row T => register-only loop, NO transpose).
// Evidence r1-r7: every structure paying the u-transpose inside the serial
// chain (LDS round-trip, barrier, or slow K16 MFMA) lands at 1340-1960
// cy/iter. Fix: absorb the transpose into T's ROW ORDER at setup time.
// With sigma_t0(4q+r)=8q+r, sigma_t1(4q+r)=8q+4+r, sigma_t2(rho)=32+rho,
// the D-output registers {W_t0, W_t1} of lane (q,l15) are exactly the
// next B-fragment's k=8q+j values (chunk 0), and W_t2 gives chunk 1's
// k=32..35 (lanes q>=1 hold pad rows whose u stays identically 0).
// Loop body: 12x clip (~60 VALU) + 3x packPairs (~36 VALU) + 18 K32 MFMAs
// in 3 independent 6-deep chains. No LDS, no barrier, no cross-lane ops.
// Bounds: bl_t0 = blp[8q..8q+3], bl_t1 = blp[8q+4..], bl_t2 = blp[32+4q..]
// (blp unchanged, pads at 36+ = +/-1e30). Output: lane q<3 stores t0 at
// col 8q, t1 at col 8q+4 (n<24 coverage exact).
// Epilogue: X_100 = base + T*u_99 (yy cancels), tiles 0,1 only.
// ---------------------------------------------------------------------------
__global__ __launch_bounds__(64) void admm_mfma(
    const float* __restrict__ raw,
    const ushort* __restrict__ Th, const ushort* __restrict__ Tl,
    const ushort* __restrict__ T0h, const ushort* __restrict__ T0l,
    const float* __restrict__ blp, const float* __restrict__ bup,
    float* __restrict__ outp) {
  const int lane = threadIdx.x & 63;
  const int l15 = lane & 15, q = lane >> 4;
  const long rowbase = (long)blockIdx.x * 16;

  // bounds per sigma mapping (contiguous, 16B-aligned)
  f32x4 bl[3], bu[3];
  bl[0] = *(const f32x4*)(blp + 8 * q);
  bu[0] = *(const f32x4*)(bup + 8 * q);
  bl[1] = *(const f32x4*)(blp + 8 * q + 4);
  bu[1] = *(const f32x4*)(bup + 8 * q + 4);
  bl[2] = *(const f32x4*)(blp + 32 + 4 * q);
  bu[2] = *(const f32x4*)(bup + 32 + 4 * q);

  // ---- peel: base = W_1 = T0' * q^T (T0 rows permuted at setup) ----------
  f32x4 W[3], base[3];
  {
    bf16x8 t0h[3], t0l[3];
#pragma unroll
    for (int t = 0; t < 3; ++t) {
      t0h[t] = *(const bf16x8*)(T0h + (16 * t + l15) * 32 + q * 8);
      t0l[t] = *(const bf16x8*)(T0l + (16 * t + l15) * 32 + q * 8);
    }
    float qa[8];
    if (q < 3) {
      const float* rp = raw + (rowbase + l15) * 24 + q * 8;
      float4 v0 = *(const float4*)rp;
      float4 v1 = *(const float4*)(rp + 4);
      qa[0] = v0.x; qa[1] = v0.y; qa[2] = v0.z; qa[3] = v0.w;
      qa[4] = v1.x; qa[5] = v1.y; qa[6] = v1.z; qa[7] = v1.w;
    } else {
#pragma unroll
      for (int j = 0; j < 8; ++j) qa[j] = 0.0f;
    }
    bf16x8 qhi, qlo;
    splitPack(qa, qhi, qlo);
#pragma unroll
    for (int t = 0; t < 3; ++t) {
      f32x4 acc = {0.0f, 0.0f, 0.0f, 0.0f};
      acc = __builtin_amdgcn_mfma_f32_16x16x32_bf16(t0h[t], qhi, acc, 0, 0, 0);
      acc = __builtin_amdgcn_mfma_f32_16x16x32_bf16(t0h[t], qlo, acc, 0, 0, 0);
      acc = __builtin_amdgcn_mfma_f32_16x16x32_bf16(t0l[t], qhi, acc, 0, 0, 0);
      base[t] = acc; W[t] = acc;
    }
  }

  // ---- T A-fragments (permuted rows): th[t][c] = T'[16t+l15][32c+8q+j] ----
  bf16x8 th[3][2], tl[3][2];
#pragma unroll
  for (int t = 0; t < 3; ++t)
#pragma unroll
    for (int c = 0; c < 2; ++c) {
      th[t][c] = *(const bf16x8*)(Th + (16 * t + l15) * 64 + 32 * c + q * 8);
      tl[t][c] = *(const bf16x8*)(Tl + (16 * t + l15) * 64 + 32 * c + q * 8);
    }

  // clip W -> u per tile, C = base + (W-Z); u stays in registers
#define CLIPU(t, U_, CC)                                             \
  _Pragma("unroll") for (int r = 0; r < 4; ++r) {                    \
    float w_ = W[t][r];                                              \
    float z_ = fminf(fmaxf(w_, bl[t][r]), bu[t][r]);                 \
    float yy_ = w_ - z_;                                             \
    U_[r] = z_ - yy_;                                                \
    CC[r] = base[t][r] + yy_;                                        \
  }

#pragma unroll 1
  for (int it = 2; it < ADMM_ITERS; ++it) {   // 98 updates: W_1 -> W_99
    f32x4 u0, u1, u2, C0, C1, C2;
    CLIPU(0, u0, C0);
    CLIPU(1, u1, C1);
    CLIPU(2, u2, C2);
    union { uint d[4]; bf16x8 v; } uh0, ul0, uh1, ul1;
    packPairs(u0, uh0.d[0], uh0.d[1], ul0.d[0], ul0.d[1]);
    packPairs(u1, uh0.d[2], uh0.d[3], ul0.d[2], ul0.d[3]);
    packPairs(u2, uh1.d[0], uh1.d[1], ul1.d[0], ul1.d[1]);
    uh1.d[2] = 0; uh1.d[3] = 0; ul1.d[2] = 0; ul1.d[3] = 0;
    f32x4 a0 = C0, a1 = C1, a2 = C2;
    a0 = __builtin_amdgcn_mfma_f32_16x16x32_bf16(th[0][0], uh0.v, a0, 0, 0, 0);
    a1 = __builtin_amdgcn_mfma_f32_16x16x32_bf16(th[1][0], uh0.v, a1, 0, 0, 0);
    a2 = __builtin_amdgcn_mfma_f32_16x16x32_bf16(th[2][0], uh0.v, a2, 0, 0, 0);
    a0 = __builtin_amdgcn_mfma_f32_16x16x32_bf16(th[0][1], uh1.v, a0, 0, 0, 0);
    a1 = __builtin_amdgcn_mfma_f32_16x16x32_bf16(th[1][1], uh1.v, a1, 0, 0, 0);
    a2 = __builtin_amdgcn_mfma_f32_16x16x32_bf16(th[2][1], uh1.v, a2, 0, 0, 0);
    a0 = __builtin_amdgcn_mfma_f32_16x16x32_bf16(th[0][0], ul0.v, a0, 0, 0, 0);
    a1 = __builtin_amdgcn_mfma_f32_16x16x32_bf16(th[1][0], ul0.v, a1, 0, 0, 0);
    a2 = __builtin_amdgcn_mfma_f32_16x16x32_bf16(th[2][0], ul0.v, a2, 0, 0, 0);
    a0 = __builtin_amdgcn_mfma_f32_16x16x32_bf16(th[0][1], ul1.v, a0, 0, 0, 0);
    a1 = __builtin_amdgcn_mfma_f32_16x16x32_bf16(th[1][1], ul1.v, a1, 0, 0, 0);
    a2 = __builtin_amdgcn_mfma_f32_16x16x32_bf16(th[2][1], ul1.v, a2, 0, 0, 0);
    a0 = __builtin_amdgcn_mfma_f32_16x16x32_bf16(tl[0][0], uh0.v, a0, 0, 0, 0);
    a1 = __builtin_amdgcn_mfma_f32_16x16x32_bf16(tl[1][0], uh0.v, a1, 0, 0, 0);
    a2 = __builtin_amdgcn_mfma_f32_16x16x32_bf16(tl[2][0], uh0.v, a2, 0, 0, 0);
    a0 = __builtin_amdgcn_mfma_f32_16x16x32_bf16(tl[0][1], uh1.v, a0, 0, 0, 0);
    a1 = __builtin_amdgcn_mfma_f32_16x16x32_bf16(tl[1][1], uh1.v, a1, 0, 0, 0);
    a2 = __builtin_amdgcn_mfma_f32_16x16x32_bf16(tl[2][1], uh1.v, a2, 0, 0, 0);
    W[0] = a0; W[1] = a1; W[2] = a2;
  }

  // ---- epilogue: X_100 = base + T*u_99 (yy cancels); tiles 0,1 only -------
  {
    f32x4 u0, u1, u2, C0, C1, C2;
    CLIPU(0, u0, C0);
    CLIPU(1, u1, C1);
    CLIPU(2, u2, C2);
    union { uint d[4]; bf16x8 v; } uh0, ul0, uh1, ul1;
    packPairs(u0, uh0.d[0], uh0.d[1], ul0.d[0], ul0.d[1]);
    packPairs(u1, uh0.d[2], uh0.d[3], ul0.d[2], ul0.d[3]);
    packPairs(u2, uh1.d[0], uh1.d[1], ul1.d[0], ul1.d[1]);
    uh1.d[2] = 0; uh1.d[3] = 0; ul1.d[2] = 0; ul1.d[3] = 0;
    f32x4 x0 = base[0], x1 = base[1];
    x0 = __builtin_amdgcn_mfma_f32_16x16x32_bf16(th[0][0], uh0.v, x0, 0, 0, 0);
    x1 = __builtin_amdgcn_mfma_f32_16x16x32_bf16(th[1][0], uh0.v, x1, 0, 0, 0);
    x0 = __builtin_amdgcn_mfma_f32_16x16x32_bf16(th[0][1], uh1.v, x0, 0, 0, 0);
    x1 = __builtin_amdgcn_mfma_f32_16x16x32_bf16(th[1][1], uh1.v, x1, 0, 0, 0);
    x0 = __builtin_amdgcn_mfma_f32_16x16x32_bf16(th[0][0], ul0.v, x0, 0, 0, 0);
    x1 = __builtin_amdgcn_mfma_f32_16x16x32_bf16(th[1][0], ul0.v, x1, 0, 0, 0);
    x0 = __builtin_amdgcn_mfma_f32_16x16x32_bf16(th[0][1], ul1.v, x0, 0, 0, 0);
    x1 = __builtin_amdgcn_mfma_f32_16x16x32_bf16(th[1][1], ul1.v, x1, 0, 0, 0);
    x0 = __builtin_amdgcn_mfma_f32_16x16x32_bf16(tl[0][0], uh0.v, x0, 0, 0, 0);
    x1 = __builtin_amdgcn_mfma_f32_16x16x32_bf16(tl[1][0], uh0.v, x1, 0, 0, 0);
    x0 = __builtin_amdgcn_mfma_f32_16x16x32_bf16(tl[0][1], uh1.v, x0, 0, 0, 0);
    x1 = __builtin_amdgcn_mfma_f32_16x16x32_bf16(tl[1][1], uh1.v, x1, 0, 0, 0);
    if (q < 3) {
      float* op = outp + (rowbase + l15) * 24 + 8 * q;
      *(f32x4*)op = x0;
      *(f32x4*)(op + 4) = x1;
    }
  }
#undef CLIPU
}

// ---------------------------------------------------------------------------
extern "C" void kernel_launch(void* const* d_in, const int* in_sizes, int n_in,
                              void* d_out, int out_size, void* d_ws, size_t ws_size,
                              hipStream_t stream) {
  const float* state = (const float*)d_in[0];
  const float* Aeq   = (const float*)d_in[1];
  const float* beq   = (const float*)d_in[2];
  const float* Ain   = (const float*)d_in[3];
  const float* bin   = (const float*)d_in[4];
  const float* ub    = (const float*)d_in[5];
  const float* lb    = (const float*)d_in[6];
  const float* W1    = (const float*)d_in[7];
  const float* b1    = (const float*)d_in[8];
  const float* W2    = (const float*)d_in[9];
  const float* b2    = (const float*)d_in[10];
  const float* W3    = (const float*)d_in[11];
  const float* b3    = (const float*)d_in[12];

  const int Bn = in_sizes[0] / 512;            // 16384
  char* ws = (char*)d_ws;
  ushort* stateB = (ushort*)(ws + 0);          // 16384x512 bf16  (16 MB)
  ushort* W1T    = (ushort*)(ws + 16777216);   // 1024x512        (1 MB)
  ushort* W2T    = (ushort*)(ws + 17825792);   // 1024x1024       (2 MB)
  ushort* W3T    = (ushort*)(ws + 19922944);   // 32x1024 (rows>=24 zero)
  ushort* Th     = (ushort*)(ws + 19993600);   // 48x64 bf16 hi (rows permuted)
  ushort* Tl     = (ushort*)(ws + 19999744);   // 48x64 bf16 lo
  ushort* T0h    = (ushort*)(ws + 20005888);   // 48x32 bf16 hi (rows permuted)
  ushort* T0l    = (ushort*)(ws + 20008960);   // 48x32 bf16 lo
  float*  blp    = (float*) (ws + 20012032);   // 48
  float*  bup    = (float*) (ws + 20012224);   // 48
  ushort* H1     = (ushort*)(ws + 21565440);   // 16384x1024 bf16 (32 MB)
  ushort* H2     = (ushort*)(ws + 55119872);   // 16384x1024 bf16 (32 MB)
  float*  rawb   = (float*)d_out;              // gemm3 out = admm in (in-place)

  const int n4 = (Bn * 512) / 4;
  const int nConv = n4 / 256;                  // 8192
  const int nPrep = nConv + 512 + 1024 + 32 + 1;
  prep_all<<<nPrep, 256, 0, stream>>>(state, stateB, n4, W1, W1T, W2, W2T, W3, W3T,
                                      Aeq, beq, Ain, bin, ub, lb,
                                      Th, Tl, T0h, T0l, blp, bup);

  const int nblkN = 1024 / 256;                // 4
  const int nwg = (Bn / 256) * nblkN;          // 256 (div by 8 -> swizzle ok)
  gemm8p<<<nwg, 512, 0, stream>>>(stateB, W1T, b1, H1, 512, 1024, nblkN);
  gemm8p<<<nwg, 512, 0, stream>>>(H1, W2T, b2, H2, 1024, 1024, nblkN);
  gemm_bt<64, 32, 4, 1, 1, 2, 1><<<dim3(1, Bn / 64), 256, 0, stream>>>(
      H2, W3T, b3, rawb, 1024, 24, 24);

  // one 16-row batch group per wave; register-only serial loop
  admm_mfma<<<Bn / 16, 64, 0, stream>>>(rawb, Th, Tl, T0h, T0l, blp, bup,
                                        (float*)d_out);
}

// Round 9
// 263.590 us; speedup vs baseline: 1.0150x; 1.0150x over previous
//
#include <hip/hip_runtime.h>

using uint = unsigned int;
using ushort = unsigned short;

typedef __attribute__((ext_vector_type(8))) short bf16x8;
typedef __attribute__((ext_vector_type(4))) short bf16x4;
typedef __attribute__((ext_vector_type(4))) float f32x4;

#define ADMM_ITERS 100
#define RHO_C 1.0f
#define SIGMA_C 1e-6f

__device__ inline ushort f2bf(float f) {
  union { float f; uint u; } c; c.f = f;
  uint u = c.u;
  uint r = (u + 0x7fffu + ((u >> 16) & 1u)) >> 16;
  return (ushort)r;
}

__device__ inline void gload_lds16(const void* g, void* l) {
  __builtin_amdgcn_global_load_lds(
      (const __attribute__((address_space(1))) void*)g,
      (__attribute__((address_space(3))) void*)l, 16, 0, 0);
}

// Split 8 f32 -> hi/lo bf16x8 by TRUNCATION (hi = mantissa-masked; lo = exact
// residual, truncated). Residual error ~2^-16 relative.
__device__ inline void splitPack(const float* x, bf16x8& hi, bf16x8& lo) {
#pragma unroll
  for (int j = 0; j < 8; ++j) {
    uint b = __float_as_uint(x[j]);
    uint hb = b & 0xffff0000u;
    float lf = x[j] - __uint_as_float(hb);
    hi[j] = (short)(b >> 16);
    lo[j] = (short)(__float_as_uint(lf) >> 16);
  }
}

// 4 f32 -> two hi-pair dwords + two lo-pair dwords (truncation split, even
// element in low 16 bits). Bit-identical values to splitPack.
__device__ inline void packPairs(const f32x4& x, uint& h0, uint& h1,
                                 uint& l0, uint& l1) {
  uint b0 = __float_as_uint(x[0]), b1 = __float_as_uint(x[1]);
  uint b2 = __float_as_uint(x[2]), b3 = __float_as_uint(x[3]);
  float r0 = x[0] - __uint_as_float(b0 & 0xffff0000u);
  float r1 = x[1] - __uint_as_float(b1 & 0xffff0000u);
  float r2 = x[2] - __uint_as_float(b2 & 0xffff0000u);
  float r3 = x[3] - __uint_as_float(b3 & 0xffff0000u);
  h0 = __builtin_amdgcn_perm(b1, b0, 0x07060302u);
  h1 = __builtin_amdgcn_perm(b3, b2, 0x07060302u);
  l0 = __builtin_amdgcn_perm(__float_as_uint(r1), __float_as_uint(r0), 0x07060302u);
  l1 = __builtin_amdgcn_perm(__float_as_uint(r3), __float_as_uint(r2), 0x07060302u);
}

// Row permutation for T/T0 storage (round-8, HW-verified): global row n ->
// tile-local position; makes the MFMA D-output register layout IDENTICAL to
// the next iteration's B-fragment layout -> u-transpose is free.
__device__ inline int permrow(int n) {
  if (n < 32) {
    int j = n & 7;
    return ((j >> 2) << 4) + ((n >> 3) << 2) + (j & 3);
  }
  return n;   // 32..35 real, 36..47 pad
}

// ---------------------------------------------------------------------------
// prep bodies (fused into prep_all)
// ---------------------------------------------------------------------------
__device__ void transpose_body(const float* __restrict__ in, ushort* __restrict__ out,
                               int R, int C, int Cout, int bx, int by, int tid) {
  __shared__ float t[32][33];
  const int c0 = bx * 32, r0 = by * 32;
  const int tx = tid & 31, ty = tid >> 5;
  for (int rr = ty; rr < 32; rr += 8) {
    int r = r0 + rr, c = c0 + tx;
    float v = 0.0f;
    if (r < R && c < C) v = in[(long)r * C + c];
    t[rr][tx] = v;
  }
  __syncthreads();
  for (int rr = ty; rr < 32; rr += 8) {
    int c = c0 + rr, r = r0 + tx;
    if (c < Cout && r < R) out[(long)c * R + r] = f2bf(t[tx][rr]);
  }
}

// ADMM setup -> MFMA operand form. T/T0 rows stored PERMUTED via permrow(n).
__device__ void setup_body(const float* __restrict__ Aeq, const float* __restrict__ beq,
                           const float* __restrict__ A, const float* __restrict__ b,
                           const float* __restrict__ ub, const float* __restrict__ lb,
                           ushort* __restrict__ Th, ushort* __restrict__ Tl,
                           ushort* __restrict__ T0h, ushort* __restrict__ T0l,
                           float* __restrict__ blp, float* __restrict__ bup, int t) {
  __shared__ float Aug[24][48];
  __shared__ float A12[12 * 24];
  __shared__ float fac[24];
  __shared__ float Tx[24][36];
  for (int i = t; i < 48 * 64; i += 256) { Th[i] = 0; Tl[i] = 0; }
  for (int i = t; i < 48 * 32; i += 256) { T0h[i] = 0; T0l[i] = 0; }
  if (t < 96)  A12[t] = Aeq[t];
  if (t < 192) A12[96 + t] = A[t];
  __syncthreads();
  for (int idx = t; idx < 576; idx += 256) {
    int j = idx / 24, k = idx % 24;
    float s = (j == k) ? (1.0f + SIGMA_C + 2.0f * RHO_C) : 0.0f;
    for (int r = 0; r < 12; ++r) s += RHO_C * A12[r * 24 + j] * A12[r * 24 + k];
    Aug[j][k] = s;
    Aug[j][24 + k] = (j == k) ? 1.0f : 0.0f;
  }
  __syncthreads();
  for (int p = 0; p < 24; ++p) {
    float rp = 1.0f / Aug[p][p];
    if (t < 24) fac[t] = Aug[t][p];
    __syncthreads();
    if (t < 48) Aug[p][t] *= rp;
    __syncthreads();
    for (int idx = t; idx < 24 * 48; idx += 256) {
      int r = idx / 48, c = idx % 48;
      if (r != p) Aug[r][c] -= fac[r] * Aug[p][c];
    }
    __syncthreads();
  }
  auto splitStore = [](ushort* hp, ushort* lp, int i, float v) {
    ushort hs = f2bf(v);
    float hf = __uint_as_float(((uint)hs) << 16);
    ushort ls = f2bf(v - hf);
    hp[i] = hs; lp[i] = ls;
  };
  for (int idx = t; idx < 24 * 36; idx += 256) {
    int n = idx / 36, k = idx % 36;
    float v;
    if (k < 24) v = 2.0f * Aug[n][24 + k];
    else {
      v = 0.0f;
      for (int j = 0; j < 24; ++j) v += Aug[n][24 + j] * A12[(k - 24) * 24 + j];
    }
    Tx[n][k] = v;
    splitStore(Th, Tl, permrow(n) * 64 + k, v);
  }
  __syncthreads();
  for (int idx = t; idx < 12 * 36; idx += 256) {
    int m = idx / 36, k = idx % 36;
    float v = 0.0f;
    for (int j = 0; j < 24; ++j) v += A12[m * 24 + j] * Tx[j][k];
    splitStore(Th, Tl, permrow(24 + m) * 64 + k, v);
  }
  for (int idx = t; idx < 36 * 24; idx += 256) {
    int n = idx / 24, k = idx % 24;
    float v;
    if (n < 24) v = Aug[n][24 + k];
    else {
      v = 0.0f;
      for (int j = 0; j < 24; ++j) v += A12[(n - 24) * 24 + j] * Aug[j][24 + k];
    }
    splitStore(T0h, T0l, permrow(n) * 32 + k, v);
  }
  if (t < 48) {
    float lv, uv;
    if (t < 24)      { lv = lb[t]; uv = ub[t]; }
    else if (t < 28) { lv = beq[t - 24]; uv = lv; }
    else if (t < 36) { lv = -1e30f; uv = b[t - 28]; }
    else             { lv = -1e30f; uv = 1e30f; }
    blp[t] = lv; bup[t] = uv;
  }
}

// Fused prep: [0,nConv) convert | [+512) W1T | [+1024) W2T | [+32) W3T | [1) setup
__global__ void prep_all(
    const float* __restrict__ state, ushort* __restrict__ stateB, int n4,
    const float* __restrict__ W1, ushort* __restrict__ W1T,
    const float* __restrict__ W2, ushort* __restrict__ W2T,
    const float* __restrict__ W3, ushort* __restrict__ W3T,
    const float* __restrict__ Aeq, const float* __restrict__ beq,
    const float* __restrict__ A, const float* __restrict__ b,
    const float* __restrict__ ub, const float* __restrict__ lb,
    ushort* __restrict__ Th, ushort* __restrict__ Tl,
    ushort* __restrict__ T0h, ushort* __restrict__ T0l,
    float* __restrict__ blp, float* __restrict__ bup) {
  const int nConv = n4 >> 8;
  int bb = blockIdx.x;
  if (bb < nConv) {
    int i = bb * 256 + threadIdx.x;
    if (i < n4) {
      float4 v = ((const float4*)state)[i];
      uint2 p;
      p.x = (uint)f2bf(v.x) | ((uint)f2bf(v.y) << 16);
      p.y = (uint)f2bf(v.z) | ((uint)f2bf(v.w) << 16);
      ((uint2*)stateB)[i] = p;
    }
    return;
  }
  bb -= nConv;
  if (bb < 512)  { transpose_body(W1, W1T, 512, 1024, 1024, bb & 31, bb >> 5, threadIdx.x); return; }
  bb -= 512;
  if (bb < 1024) { transpose_body(W2, W2T, 1024, 1024, 1024, bb & 31, bb >> 5, threadIdx.x); return; }
  bb -= 1024;
  if (bb < 32)   { transpose_body(W3, W3T, 1024, 24, 32, 0, bb, threadIdx.x); return; }
  setup_body(Aeq, beq, A, b, ub, lb, Th, Tl, T0h, T0l, blp, bup, threadIdx.x);
}

// ---------------------------------------------------------------------------
// bf16 GEMM, C = A[M,K] * Bt[N,K]^T — m97-style staging (skinny final layer).
// ---------------------------------------------------------------------------
template<int BM, int BN, int WM, int WN, int TM, int TN, int MODE>
__global__ __launch_bounds__(256) void gemm_bt(
    const ushort* __restrict__ A, const ushort* __restrict__ Bt,
    const float* __restrict__ bias, void* __restrict__ Cout_,
    int K, int ldc, int nvalid) {
  __shared__ char lds[(BM + BN) * 64];
  char* ldsA = lds;
  char* ldsB = lds + BM * 64;

  const int tid = threadIdx.x;
  const int wave = tid >> 6;
  const int lane = tid & 63;
  const int blockM = blockIdx.y * BM;
  const int blockN = blockIdx.x * BN;
  const int wm = (wave / WN) * (TM * 16);
  const int wn = (wave % WN) * (TN * 16);

  f32x4 acc[TM][TN] = {};

  const int l15 = lane & 15;
  const int kq = lane >> 4;
  constexpr int AI = BM / 16;
  constexpr int TOT = (BM + BN) / 16;
  const int srow = lane >> 2;
  const int kb = (lane & 3) ^ ((srow >> 1) & 3);

  for (int k0 = 0; k0 < K; k0 += 32) {
    for (int inst = wave; inst < TOT; inst += 4) {
      const bool isA = inst < AI;
      const int i = isA ? inst : inst - AI;
      const ushort* gp = (isA ? A : Bt)
          + (long)((isA ? blockM : blockN) + i * 16 + srow) * K + (k0 + kb * 8);
      char* lp = (isA ? ldsA : ldsB) + i * 1024;
      gload_lds16(gp, lp);
    }
    __syncthreads();

    bf16x8 af[TM], bfr[TN];
#pragma unroll
    for (int i = 0; i < TM; ++i) {
      int r = wm + i * 16 + l15;
      int ch = kq ^ ((r >> 1) & 3);
      af[i] = *(const bf16x8*)(ldsA + r * 64 + ch * 16);
    }
#pragma unroll
    for (int j = 0; j < TN; ++j) {
      int r = wn + j * 16 + l15;
      int ch = kq ^ ((r >> 1) & 3);
      bfr[j] = *(const bf16x8*)(ldsB + r * 64 + ch * 16);
    }
#pragma unroll
    for (int i = 0; i < TM; ++i)
#pragma unroll
      for (int j = 0; j < TN; ++j)
        acc[i][j] = __builtin_amdgcn_mfma_f32_16x16x32_bf16(af[i], bfr[j], acc[i][j], 0, 0, 0);
    __syncthreads();
  }

  const int ro = lane >> 4;
#pragma unroll
  for (int i = 0; i < TM; ++i) {
#pragma unroll
    for (int j = 0; j < TN; ++j) {
      const int col = blockN + wn + j * 16 + l15;
      float bv;
      if (MODE == 0) bv = bias[col];
      else bv = (col < nvalid) ? bias[col] : 0.0f;
#pragma unroll
      for (int r = 0; r < 4; ++r) {
        const int row = blockM + wm + i * 16 + ro * 4 + r;
        float v = acc[i][j][r] + bv;
        if (MODE == 0) {
          v = fmaxf(v, 0.0f);
          ((ushort*)Cout_)[(long)row * ldc + col] = f2bf(v);
        } else {
          if (col < nvalid) ((float*)Cout_)[(long)row * ldc + col] = v;
        }
      }
    }
  }
}

// ---------------------------------------------------------------------------
// 256x256 8-phase bf16 GEMM (T1+T2+T3+T4+T5) — unchanged.
// ---------------------------------------------------------------------------
#define GEMM8P_QUAD(MI0, NJ0)                                                 \
  _Pragma("unroll") for (int mi_ = 0; mi_ < 4; ++mi_)                         \
  _Pragma("unroll") for (int nj_ = 0; nj_ < 2; ++nj_)                         \
  _Pragma("unroll") for (int kk_ = 0; kk_ < 2; ++kk_)                         \
    acc[(MI0) + mi_][(NJ0) + nj_] = __builtin_amdgcn_mfma_f32_16x16x32_bf16(  \
        aF[mi_][kk_], bF[(NJ0) + nj_][kk_], acc[(MI0) + mi_][(NJ0) + nj_],    \
        0, 0, 0);

#define GEMM8P_SYNC_PRE()                              \
  __builtin_amdgcn_s_barrier();                        \
  asm volatile("s_waitcnt lgkmcnt(0)" ::: "memory");   \
  __builtin_amdgcn_sched_barrier(0);                   \
  __builtin_amdgcn_s_setprio(1);

#define GEMM8P_SYNC_POST()                             \
  __builtin_amdgcn_s_setprio(0);                       \
  __builtin_amdgcn_s_barrier();

__global__ __launch_bounds__(512, 2) void gemm8p(
    const ushort* __restrict__ A, const ushort* __restrict__ Bt,
    const float* __restrict__ bias, ushort* __restrict__ Cout,
    int K, int ldc, int nblk_n) {
  __shared__ __align__(16) char ldsc[131072];   // [2 buf][A 32K | B 32K]

  const int nwg = gridDim.x;
  const int bid = blockIdx.x;
  const int swz = (bid & 7) * (nwg >> 3) + (bid >> 3);
  const int blockM = (swz / nblk_n) * 256;
  const int blockN = (swz % nblk_n) * 256;

  const int tid = threadIdx.x;
  const int wave = tid >> 6;
  const int lane = tid & 63;
  const int l15 = lane & 15;
  const int q = lane >> 4;
  const int wm = (wave >> 2) * 128;
  const int wn = (wave & 3) * 64;
  const int nt = K >> 6;

  f32x4 acc[8][4] = {};

  auto stage = [&](int ts, int h) {
    if (ts >= nt) return;
    char* base = ldsc + ((ts & 1) << 16) + (h << 14);
#pragma unroll
    for (int j = 0; j < 2; ++j) {
      const int idx = wave * 64 + j * 512 + lane;
      const int row = idx >> 3;
      const int cs = (idx & 7) ^ (row & 7);
      const ushort* gp =
          (h < 2 ? A + (long)(blockM + ((h & 1) << 7) + row) * K
                 : Bt + (long)(blockN + ((h & 1) << 7) + row) * K)
          + (ts << 6) + cs * 8;
      gload_lds16(gp, base + ((wave * 64 + j * 512) << 4));
    }
  };
  auto dsA = [&](int cb, int mi, int kk) {
    const int r = wm + mi * 16 + l15;
    const int cs = (kk * 4 + q) ^ (r & 7);
    return *(const bf16x8*)(ldsc + (cb << 16) + r * 128 + cs * 16);
  };
  auto dsB = [&](int cb, int nj, int kk) {
    const int r = wn + nj * 16 + l15;
    const int cs = (kk * 4 + q) ^ (r & 7);
    return *(const bf16x8*)(ldsc + (cb << 16) + 32768 + r * 128 + cs * 16);
  };

  stage(0, 0); stage(0, 1); stage(0, 2); stage(0, 3);
  stage(1, 0);
  asm volatile("s_waitcnt vmcnt(2)" ::: "memory");
  __builtin_amdgcn_s_barrier();

  bf16x8 aF[4][2], bF[4][2];
#pragma unroll 1
  for (int t = 0; t < nt; ++t) {
    const int cb = t & 1;
#pragma unroll
    for (int mi = 0; mi < 4; ++mi)
#pragma unroll
      for (int kk = 0; kk < 2; ++kk) aF[mi][kk] = dsA(cb, mi, kk);
#pragma unroll
    for (int nj = 0; nj < 2; ++nj)
#pragma unroll
      for (int kk = 0; kk < 2; ++kk) bF[nj][kk] = dsB(cb, nj, kk);
    stage(t + 1, 1);
    GEMM8P_SYNC_PRE();
    GEMM8P_QUAD(0, 0);
    GEMM8P_SYNC_POST();
#pragma unroll
    for (int nj = 2; nj < 4; ++nj)
#pragma unroll
      for (int kk = 0; kk < 2; ++kk) bF[nj][kk] = dsB(cb, nj, kk);
    stage(t + 1, 2);
    GEMM8P_SYNC_PRE();
    GEMM8P_QUAD(0, 2);
    GEMM8P_SYNC_POST();
#pragma unroll
    for (int mi = 0; mi < 4; ++mi)
#pragma unroll
      for (int kk = 0; kk < 2; ++kk) aF[mi][kk] = dsA(cb, 4 + mi, kk);
    stage(t + 1, 3);
    GEMM8P_SYNC_PRE();
    GEMM8P_QUAD(4, 2);
    GEMM8P_SYNC_POST();
    stage(t + 2, 0);
    if (t + 2 < nt) { asm volatile("s_waitcnt vmcnt(2)" ::: "memory"); }
    else            { asm volatile("s_waitcnt vmcnt(0)" ::: "memory"); }
    __builtin_amdgcn_s_barrier();
    __builtin_amdgcn_s_setprio(1);
    GEMM8P_QUAD(4, 0);
    GEMM8P_SYNC_POST();
  }

#pragma unroll
  for (int mi = 0; mi < 8; ++mi) {
#pragma unroll
    for (int nj = 0; nj < 4; ++nj) {
      const int col = blockN + wn + nj * 16 + l15;
      const float bv = bias[col];
#pragma unroll
      for (int r = 0; r < 4; ++r) {
        const int row = blockM + wm + mi * 16 + q * 4 + r;
        float v = acc[mi][nj][r] + bv;
        v = fmaxf(v, 0.0f);
        Cout[(long)row * ldc + col] = f2bf(v);
      }
    }
  }
}

// ---------------------------------------------------------------------------
// ADMM via MFMA (round-9: TWO groups per wave, software-pipelined).
// r8 post-mortem: register-only loop = 1800 cy/iter vs ~650 floor (MFMA pipe
// 18 x 19.4cy/SIMD + VALU ~250; strict V->M->V alternation, 1 wave/SIMD, no
// filler). Fix: one wave owns two independent 16-row groups G,H and rotates
//   VALU_G | loop{ MFMA_G ; VALU_H ; MFMA_H ; VALU_G(next) } | drain
// so each group's VALU issues under the other group's MFMA pipe time. T
// fragments + bounds shared (72 VGPR); only W/base/u duplicate. Same
// HW-verified permuted-T math as r8 (bit-identical per group).
// Decisive: if dur is unchanged, the chain is irreducible dep-path ->
// admm at floor, pivot to GEMMs.
// ---------------------------------------------------------------------------
#define MF(a, b, c) __builtin_amdgcn_mfma_f32_16x16x32_bf16(a, b, c, 0, 0, 0)

#define CLIP4(Wv, basev, t, Uv, Cv)                                  \
  _Pragma("unroll") for (int r = 0; r < 4; ++r) {                    \
    float w_ = Wv[t][r];                                             \
    float z_ = fminf(fmaxf(w_, bl[t][r]), bu[t][r]);                 \
    float yy_ = w_ - z_;                                             \
    Uv[r] = z_ - yy_;                                                \
    Cv[r] = basev[t][r] + yy_;                                       \
  }

// clip+pack all 3 tiles of one group -> operands UH0,UL0,UH1,UL1 + C0..C2
#define VALU_GRP(Wv, basev, UH0, UL0, UH1, UL1, C0, C1, C2)          \
  {                                                                  \
    f32x4 u0_, u1_, u2_;                                             \
    CLIP4(Wv, basev, 0, u0_, C0);                                    \
    CLIP4(Wv, basev, 1, u1_, C1);                                    \
    CLIP4(Wv, basev, 2, u2_, C2);                                    \
    union { uint d[4]; bf16x8 v; } h0_, l0_, h1_, l1_;               \
    packPairs(u0_, h0_.d[0], h0_.d[1], l0_.d[0], l0_.d[1]);          \
    packPairs(u1_, h0_.d[2], h0_.d[3], l0_.d[2], l0_.d[3]);          \
    packPairs(u2_, h1_.d[0], h1_.d[1], l1_.d[0], l1_.d[1]);          \
    h1_.d[2] = 0; h1_.d[3] = 0; l1_.d[2] = 0; l1_.d[3] = 0;          \
    UH0 = h0_.v; UL0 = l0_.v; UH1 = h1_.v; UL1 = l1_.v;              \
  }

// 18-MFMA update of one group's W from its packed operands
#define MFMA_GRP(Wv, UH0, UL0, UH1, UL1, C0, C1, C2)                 \
  {                                                                  \
    f32x4 a0_ = C0, a1_ = C1, a2_ = C2;                              \
    a0_ = MF(th[0][0], UH0, a0_);                                    \
    a1_ = MF(th[1][0], UH0, a1_);                                    \
    a2_ = MF(th[2][0], UH0, a2_);                                    \
    a0_ = MF(th[0][1], UH1, a0_);                                    \
    a1_ = MF(th[1][1], UH1, a1_);                                    \
    a2_ = MF(th[2][1], UH1, a2_);                                    \
    a0_ = MF(th[0][0], UL0, a0_);                                    \
    a1_ = MF(th[1][0], UL0, a1_);                                    \
    a2_ = MF(th[2][0], UL0, a2_);                                    \
    a0_ = MF(th[0][1], UL1, a0_);                                    \
    a1_ = MF(th[1][1], UL1, a1_);                                    \
    a2_ = MF(th[2][1], UL1, a2_);                                    \
    a0_ = MF(tl[0][0], UH0, a0_);                                    \
    a1_ = MF(tl[1][0], UH0, a1_);                                    \
    a2_ = MF(tl[2][0], UH0, a2_);                                    \
    a0_ = MF(tl[0][1], UH1, a0_);                                    \
    a1_ = MF(tl[1][1], UH1, a1_);                                    \
    a2_ = MF(tl[2][1], UH1, a2_);                                    \
    Wv[0] = a0_; Wv[1] = a1_; Wv[2] = a2_;                           \
  }

// 12-MFMA epilogue: X = base + T*u (tiles 0,1), store rows rb..rb+15
#define EPI_GRP(basev, UH0, UL0, UH1, UL1, rb)                       \
  {                                                                  \
    f32x4 x0_ = basev[0], x1_ = basev[1];                            \
    x0_ = MF(th[0][0], UH0, x0_);                                    \
    x1_ = MF(th[1][0], UH0, x1_);                                    \
    x0_ = MF(th[0][1], UH1, x0_);                                    \
    x1_ = MF(th[1][1], UH1, x1_);                                    \
    x0_ = MF(th[0][0], UL0, x0_);                                    \
    x1_ = MF(th[1][0], UL0, x1_);                                    \
    x0_ = MF(th[0][1], UL1, x0_);                                    \
    x1_ = MF(th[1][1], UL1, x1_);                                    \
    x0_ = MF(tl[0][0], UH0, x0_);                                    \
    x1_ = MF(tl[1][0], UH0, x1_);                                    \
    x0_ = MF(tl[0][1], UH1, x0_);                                    \
    x1_ = MF(tl[1][1], UH1, x1_);                                    \
    if (q < 3) {                                                     \
      float* op_ = outp + ((rb) + l15) * 24 + 8 * q;                 \
      *(f32x4*)op_ = x0_;                                            \
      *(f32x4*)(op_ + 4) = x1_;                                      \
    }                                                                \
  }

__global__ __launch_bounds__(64) void admm_mfma(
    const float* __restrict__ raw,
    const ushort* __restrict__ Th, const ushort* __restrict__ Tl,
    const ushort* __restrict__ T0h, const ushort* __restrict__ T0l,
    const float* __restrict__ blp, const float* __restrict__ bup,
    float* __restrict__ outp) {
  const int lane = threadIdx.x & 63;
  const int l15 = lane & 15, q = lane >> 4;
  const long rowG = (long)blockIdx.x * 32;
  const long rowH = rowG + 16;

  // bounds per sigma mapping (shared by both groups)
  f32x4 bl[3], bu[3];
  bl[0] = *(const f32x4*)(blp + 8 * q);
  bu[0] = *(const f32x4*)(bup + 8 * q);
  bl[1] = *(const f32x4*)(blp + 8 * q + 4);
  bu[1] = *(const f32x4*)(bup + 8 * q + 4);
  bl[2] = *(const f32x4*)(blp + 32 + 4 * q);
  bu[2] = *(const f32x4*)(bup + 32 + 4 * q);

  // ---- peel both groups: base = W_1 = T0' * q^T ---------------------------
  f32x4 WG[3], baseG[3], WH[3], baseH[3];
  {
    bf16x8 t0h[3], t0l[3];
#pragma unroll
    for (int t = 0; t < 3; ++t) {
      t0h[t] = *(const bf16x8*)(T0h + (16 * t + l15) * 32 + q * 8);
      t0l[t] = *(const bf16x8*)(T0l + (16 * t + l15) * 32 + q * 8);
    }
#pragma unroll
    for (int g = 0; g < 2; ++g) {
      const long rb = g ? rowH : rowG;
      float qa[8];
      if (q < 3) {
        const float* rp = raw + (rb + l15) * 24 + q * 8;
        float4 v0 = *(const float4*)rp;
        float4 v1 = *(const float4*)(rp + 4);
        qa[0] = v0.x; qa[1] = v0.y; qa[2] = v0.z; qa[3] = v0.w;
        qa[4] = v1.x; qa[5] = v1.y; qa[6] = v1.z; qa[7] = v1.w;
      } else {
#pragma unroll
        for (int j = 0; j < 8; ++j) qa[j] = 0.0f;
      }
      bf16x8 qhi, qlo;
      splitPack(qa, qhi, qlo);
#pragma unroll
      for (int t = 0; t < 3; ++t) {
        f32x4 acc = {0.0f, 0.0f, 0.0f, 0.0f};
        acc = MF(t0h[t], qhi, acc);
        acc = MF(t0h[t], qlo, acc);
        acc = MF(t0l[t], qhi, acc);
        if (g) { baseH[t] = acc; WH[t] = acc; }
        else   { baseG[t] = acc; WG[t] = acc; }
      }
    }
  }

  // ---- T A-fragments (permuted rows), shared ------------------------------
  bf16x8 th[3][2], tl[3][2];
#pragma unroll
  for (int t = 0; t < 3; ++t)
#pragma unroll
    for (int c = 0; c < 2; ++c) {
      th[t][c] = *(const bf16x8*)(Th + (16 * t + l15) * 64 + 32 * c + q * 8);
      tl[t][c] = *(const bf16x8*)(Tl + (16 * t + l15) * 64 + 32 * c + q * 8);
    }

  bf16x8 gH0, gL0, gH1, gL1, hH0, hL0, hH1, hL1;
  f32x4 gC0, gC1, gC2, hC0, hC1, hC2;

  // prologue: G's first VALU phase (u from W_1)
  VALU_GRP(WG, baseG, gH0, gL0, gH1, gL1, gC0, gC1, gC2);

  // rotated steady state: 97 iterations of {MFMA_G, VALU_H, MFMA_H, VALU_G}
#pragma unroll 1
  for (int it = 2; it < ADMM_ITERS - 1; ++it) {
    MFMA_GRP(WG, gH0, gL0, gH1, gL1, gC0, gC1, gC2);
    VALU_GRP(WH, baseH, hH0, hL0, hH1, hL1, hC0, hC1, hC2);
    MFMA_GRP(WH, hH0, hL0, hH1, hL1, hC0, hC1, hC2);
    VALU_GRP(WG, baseG, gH0, gL0, gH1, gL1, gC0, gC1, gC2);
  }
  // it = 99: final updates -> W_99 for both groups
  MFMA_GRP(WG, gH0, gL0, gH1, gL1, gC0, gC1, gC2);
  VALU_GRP(WH, baseH, hH0, hL0, hH1, hL1, hC0, hC1, hC2);
  MFMA_GRP(WH, hH0, hL0, hH1, hL1, hC0, hC1, hC2);

  // epilogue: X_100 = base + T*u_99 (yy cancels), both groups
  VALU_GRP(WG, baseG, gH0, gL0, gH1, gL1, gC0, gC1, gC2);
  VALU_GRP(WH, baseH, hH0, hL0, hH1, hL1, hC0, hC1, hC2);
  EPI_GRP(baseG, gH0, gL0, gH1, gL1, rowG);
  EPI_GRP(baseH, hH0, hL0, hH1, hL1, rowH);
}

// ---------------------------------------------------------------------------
extern "C" void kernel_launch(void* const* d_in, const int* in_sizes, int n_in,
                              void* d_out, int out_size, void* d_ws, size_t ws_size,
                              hipStream_t stream) {
  const float* state = (const float*)d_in[0];
  const float* Aeq   = (const float*)d_in[1];
  const float* beq   = (const float*)d_in[2];
  const float* Ain   = (const float*)d_in[3];
  const float* bin   = (const float*)d_in[4];
  const float* ub    = (const float*)d_in[5];
  const float* lb    = (const float*)d_in[6];
  const float* W1    = (const float*)d_in[7];
  const float* b1    = (const float*)d_in[8];
  const float* W2    = (const float*)d_in[9];
  const float* b2    = (const float*)d_in[10];
  const float* W3    = (const float*)d_in[11];
  const float* b3    = (const float*)d_in[12];

  const int Bn = in_sizes[0] / 512;            // 16384
  char* ws = (char*)d_ws;
  ushort* stateB = (ushort*)(ws + 0);          // 16384x512 bf16  (16 MB)
  ushort* W1T    = (ushort*)(ws + 16777216);   // 1024x512        (1 MB)
  ushort* W2T    = (ushort*)(ws + 17825792);   // 1024x1024       (2 MB)
  ushort* W3T    = (ushort*)(ws + 19922944);   // 32x1024 (rows>=24 zero)
  ushort* Th     = (ushort*)(ws + 19993600);   // 48x64 bf16 hi (rows permuted)
  ushort* Tl     = (ushort*)(ws + 19999744);   // 48x64 bf16 lo
  ushort* T0h    = (ushort*)(ws + 20005888);   // 48x32 bf16 hi (rows permuted)
  ushort* T0l    = (ushort*)(ws + 20008960);   // 48x32 bf16 lo
  float*  blp    = (float*) (ws + 20012032);   // 48
  float*  bup    = (float*) (ws + 20012224);   // 48
  ushort* H1     = (ushort*)(ws + 21565440);   // 16384x1024 bf16 (32 MB)
  ushort* H2     = (ushort*)(ws + 55119872);   // 16384x1024 bf16 (32 MB)
  float*  rawb   = (float*)d_out;              // gemm3 out = admm in (in-place)

  const int n4 = (Bn * 512) / 4;
  const int nConv = n4 / 256;                  // 8192
  const int nPrep = nConv + 512 + 1024 + 32 + 1;
  prep_all<<<nPrep, 256, 0, stream>>>(state, stateB, n4, W1, W1T, W2, W2T, W3, W3T,
                                      Aeq, beq, Ain, bin, ub, lb,
                                      Th, Tl, T0h, T0l, blp, bup);

  const int nblkN = 1024 / 256;                // 4
  const int nwg = (Bn / 256) * nblkN;          // 256 (div by 8 -> swizzle ok)
  gemm8p<<<nwg, 512, 0, stream>>>(stateB, W1T, b1, H1, 512, 1024, nblkN);
  gemm8p<<<nwg, 512, 0, stream>>>(H1, W2T, b2, H2, 1024, 1024, nblkN);
  gemm_bt<64, 32, 4, 1, 1, 2, 1><<<dim3(1, Bn / 64), 256, 0, stream>>>(
      H2, W3T, b3, rawb, 1024, 24, 24);

  // two 16-row groups per wave, software-pipelined (fills V<->M bubbles)
  admm_mfma<<<Bn / 32, 64, 0, stream>>>(rawb, Th, Tl, T0h, T0l, blp, bup,
                                        (float*)d_out);
}

// Round 10
// 247.420 us; speedup vs baseline: 1.0814x; 1.0654x over previous
//
#include <hip/hip_runtime.h>

using uint = unsigned int;
using ushort = unsigned short;

typedef __attribute__((ext_vector_type(8))) short bf16x8;
typedef __attribute__((ext_vector_type(4))) short bf16x4;
typedef __attribute__((ext_vector_type(4))) float f32x4;

#define ADMM_ITERS 100
#define RHO_C 1.0f
#define SIGMA_C 1e-6f

__device__ inline ushort f2bf(float f) {
  union { float f; uint u; } c; c.f = f;
  uint u = c.u;
  uint r = (u + 0x7fffu + ((u >> 16) & 1u)) >> 16;
  return (ushort)r;
}

__device__ inline void gload_lds16(const void* g, void* l) {
  __builtin_amdgcn_global_load_lds(
      (const __attribute__((address_space(1))) void*)g,
      (__attribute__((address_space(3))) void*)l, 16, 0, 0);
}

// Split 8 f32 -> hi/lo bf16x8 by TRUNCATION (hi = mantissa-masked; lo = exact
// residual, truncated). Residual error ~2^-16 relative.
__device__ inline void splitPack(const float* x, bf16x8& hi, bf16x8& lo) {
#pragma unroll
  for (int j = 0; j < 8; ++j) {
    uint b = __float_as_uint(x[j]);
    uint hb = b & 0xffff0000u;
    float lf = x[j] - __uint_as_float(hb);
    hi[j] = (short)(b >> 16);
    lo[j] = (short)(__float_as_uint(lf) >> 16);
  }
}

// ---------------------------------------------------------------------------
// prep bodies (fused into prep_all)
// ---------------------------------------------------------------------------
__device__ void transpose_body(const float* __restrict__ in, ushort* __restrict__ out,
                               int R, int C, int Cout, int bx, int by, int tid) {
  __shared__ float t[32][33];
  const int c0 = bx * 32, r0 = by * 32;
  const int tx = tid & 31, ty = tid >> 5;
  for (int rr = ty; rr < 32; rr += 8) {
    int r = r0 + rr, c = c0 + tx;
    float v = 0.0f;
    if (r < R && c < C) v = in[(long)r * C + c];
    t[rr][tx] = v;
  }
  __syncthreads();
  for (int rr = ty; rr < 32; rr += 8) {
    int c = c0 + rr, r = r0 + tx;
    if (c < Cout && r < R) out[(long)c * R + r] = f2bf(t[tx][rr]);
  }
}

// ADMM setup -> MFMA operand form (round-10: reverted to the round-0 layout,
// NO row permutation — pairs the round-0 admm_mfma below, which was the best
// measured admm across 9 rewrite attempts).
// W-state iteration (verified): u = 2*clip(W)-W,
//   W' = base + T*u + (W - Z),  T = [[2Minv, G],[2*A12*Minv, A12*G]] (36x36)
//   base = T0*q per row,       T0 = [[Minv],[A12*Minv]] (36x24)
// Outputs row-major [n_out][k_in], bf16 hi+lo (rounded split):
// Th/Tl [48][64], T0h/T0l [48][32], bounds bl/bu [48].
__device__ void setup_body(const float* __restrict__ Aeq, const float* __restrict__ beq,
                           const float* __restrict__ A, const float* __restrict__ b,
                           const float* __restrict__ ub, const float* __restrict__ lb,
                           ushort* __restrict__ Th, ushort* __restrict__ Tl,
                           ushort* __restrict__ T0h, ushort* __restrict__ T0l,
                           float* __restrict__ blp, float* __restrict__ bup, int t) {
  __shared__ float Aug[24][48];
  __shared__ float A12[12 * 24];
  __shared__ float fac[24];
  __shared__ float Tx[24][36];
  for (int i = t; i < 48 * 64; i += 256) { Th[i] = 0; Tl[i] = 0; }
  for (int i = t; i < 48 * 32; i += 256) { T0h[i] = 0; T0l[i] = 0; }
  if (t < 96)  A12[t] = Aeq[t];
  if (t < 192) A12[96 + t] = A[t];
  __syncthreads();
  for (int idx = t; idx < 576; idx += 256) {
    int j = idx / 24, k = idx % 24;
    float s = (j == k) ? (1.0f + SIGMA_C + 2.0f * RHO_C) : 0.0f;
    for (int r = 0; r < 12; ++r) s += RHO_C * A12[r * 24 + j] * A12[r * 24 + k];
    Aug[j][k] = s;
    Aug[j][24 + k] = (j == k) ? 1.0f : 0.0f;
  }
  __syncthreads();
  for (int p = 0; p < 24; ++p) {
    float rp = 1.0f / Aug[p][p];
    if (t < 24) fac[t] = Aug[t][p];
    __syncthreads();
    if (t < 48) Aug[p][t] *= rp;
    __syncthreads();
    for (int idx = t; idx < 24 * 48; idx += 256) {
      int r = idx / 48, c = idx % 48;
      if (r != p) Aug[r][c] -= fac[r] * Aug[p][c];
    }
    __syncthreads();
  }
  auto splitStore = [](ushort* hp, ushort* lp, int i, float v) {
    ushort hs = f2bf(v);
    float hf = __uint_as_float(((uint)hs) << 16);
    ushort ls = f2bf(v - hf);
    hp[i] = hs; lp[i] = ls;
  };
  for (int idx = t; idx < 24 * 36; idx += 256) {
    int n = idx / 36, k = idx % 36;
    float v;
    if (k < 24) v = 2.0f * Aug[n][24 + k];
    else {
      v = 0.0f;
      for (int j = 0; j < 24; ++j) v += Aug[n][24 + j] * A12[(k - 24) * 24 + j];
    }
    Tx[n][k] = v;
    splitStore(Th, Tl, n * 64 + k, v);
  }
  __syncthreads();
  for (int idx = t; idx < 12 * 36; idx += 256) {
    int m = idx / 36, k = idx % 36;
    float v = 0.0f;
    for (int j = 0; j < 24; ++j) v += A12[m * 24 + j] * Tx[j][k];
    splitStore(Th, Tl, (24 + m) * 64 + k, v);
  }
  for (int idx = t; idx < 36 * 24; idx += 256) {
    int n = idx / 24, k = idx % 24;
    float v;
    if (n < 24) v = Aug[n][24 + k];
    else {
      v = 0.0f;
      for (int j = 0; j < 24; ++j) v += A12[(n - 24) * 24 + j] * Aug[j][24 + k];
    }
    splitStore(T0h, T0l, n * 32 + k, v);
  }
  if (t < 48) {
    float lv, uv;
    if (t < 24)      { lv = lb[t]; uv = ub[t]; }
    else if (t < 28) { lv = beq[t - 24]; uv = lv; }
    else if (t < 36) { lv = -1e30f; uv = b[t - 28]; }
    else             { lv = -1e30f; uv = 1e30f; }
    blp[t] = lv; bup[t] = uv;
  }
}

// Fused prep: [0,nConv) convert | [+512) W1T | [+1024) W2T | [+32) W3T | [1) setup
__global__ void prep_all(
    const float* __restrict__ state, ushort* __restrict__ stateB, int n4,
    const float* __restrict__ W1, ushort* __restrict__ W1T,
    const float* __restrict__ W2, ushort* __restrict__ W2T,
    const float* __restrict__ W3, ushort* __restrict__ W3T,
    const float* __restrict__ Aeq, const float* __restrict__ beq,
    const float* __restrict__ A, const float* __restrict__ b,
    const float* __restrict__ ub, const float* __restrict__ lb,
    ushort* __restrict__ Th, ushort* __restrict__ Tl,
    ushort* __restrict__ T0h, ushort* __restrict__ T0l,
    float* __restrict__ blp, float* __restrict__ bup) {
  const int nConv = n4 >> 8;
  int bb = blockIdx.x;
  if (bb < nConv) {
    int i = bb * 256 + threadIdx.x;
    if (i < n4) {
      float4 v = ((const float4*)state)[i];
      uint2 p;
      p.x = (uint)f2bf(v.x) | ((uint)f2bf(v.y) << 16);
      p.y = (uint)f2bf(v.z) | ((uint)f2bf(v.w) << 16);
      ((uint2*)stateB)[i] = p;
    }
    return;
  }
  bb -= nConv;
  if (bb < 512)  { transpose_body(W1, W1T, 512, 1024, 1024, bb & 31, bb >> 5, threadIdx.x); return; }
  bb -= 512;
  if (bb < 1024) { transpose_body(W2, W2T, 1024, 1024, 1024, bb & 31, bb >> 5, threadIdx.x); return; }
  bb -= 1024;
  if (bb < 32)   { transpose_body(W3, W3T, 1024, 24, 32, 0, bb, threadIdx.x); return; }
  setup_body(Aeq, beq, A, b, ub, lb, Th, Tl, T0h, T0l, blp, bup, threadIdx.x);
}

// ---------------------------------------------------------------------------
// bf16 GEMM, C = A[M,K] * Bt[N,K]^T — m97-style staging (skinny final layer).
// ---------------------------------------------------------------------------
template<int BM, int BN, int WM, int WN, int TM, int TN, int MODE>
__global__ __launch_bounds__(256) void gemm_bt(
    const ushort* __restrict__ A, const ushort* __restrict__ Bt,
    const float* __restrict__ bias, void* __restrict__ Cout_,
    int K, int ldc, int nvalid) {
  __shared__ char lds[(BM + BN) * 64];
  char* ldsA = lds;
  char* ldsB = lds + BM * 64;

  const int tid = threadIdx.x;
  const int wave = tid >> 6;
  const int lane = tid & 63;
  const int blockM = blockIdx.y * BM;
  const int blockN = blockIdx.x * BN;
  const int wm = (wave / WN) * (TM * 16);
  const int wn = (wave % WN) * (TN * 16);

  f32x4 acc[TM][TN] = {};

  const int l15 = lane & 15;
  const int kq = lane >> 4;
  constexpr int AI = BM / 16;
  constexpr int TOT = (BM + BN) / 16;
  const int srow = lane >> 2;
  const int kb = (lane & 3) ^ ((srow >> 1) & 3);

  for (int k0 = 0; k0 < K; k0 += 32) {
    for (int inst = wave; inst < TOT; inst += 4) {
      const bool isA = inst < AI;
      const int i = isA ? inst : inst - AI;
      const ushort* gp = (isA ? A : Bt)
          + (long)((isA ? blockM : blockN) + i * 16 + srow) * K + (k0 + kb * 8);
      char* lp = (isA ? ldsA : ldsB) + i * 1024;
      gload_lds16(gp, lp);
    }
    __syncthreads();

    bf16x8 af[TM], bfr[TN];
#pragma unroll
    for (int i = 0; i < TM; ++i) {
      int r = wm + i * 16 + l15;
      int ch = kq ^ ((r >> 1) & 3);
      af[i] = *(const bf16x8*)(ldsA + r * 64 + ch * 16);
    }
#pragma unroll
    for (int j = 0; j < TN; ++j) {
      int r = wn + j * 16 + l15;
      int ch = kq ^ ((r >> 1) & 3);
      bfr[j] = *(const bf16x8*)(ldsB + r * 64 + ch * 16);
    }
#pragma unroll
    for (int i = 0; i < TM; ++i)
#pragma unroll
      for (int j = 0; j < TN; ++j)
        acc[i][j] = __builtin_amdgcn_mfma_f32_16x16x32_bf16(af[i], bfr[j], acc[i][j], 0, 0, 0);
    __syncthreads();
  }

  const int ro = lane >> 4;
#pragma unroll
  for (int i = 0; i < TM; ++i) {
#pragma unroll
    for (int j = 0; j < TN; ++j) {
      const int col = blockN + wn + j * 16 + l15;
      float bv;
      if (MODE == 0) bv = bias[col];
      else bv = (col < nvalid) ? bias[col] : 0.0f;
#pragma unroll
      for (int r = 0; r < 4; ++r) {
        const int row = blockM + wm + i * 16 + ro * 4 + r;
        float v = acc[i][j][r] + bv;
        if (MODE == 0) {
          v = fmaxf(v, 0.0f);
          ((ushort*)Cout_)[(long)row * ldc + col] = f2bf(v);
        } else {
          if (col < nvalid) ((float*)Cout_)[(long)row * ldc + col] = v;
        }
      }
    }
  }
}

// ---------------------------------------------------------------------------
// 256x256 8-phase bf16 GEMM (T1+T2+T3+T4+T5) — unchanged.
// ---------------------------------------------------------------------------
#define GEMM8P_QUAD(MI0, NJ0)                                                 \
  _Pragma("unroll") for (int mi_ = 0; mi_ < 4; ++mi_)                         \
  _Pragma("unroll") for (int nj_ = 0; nj_ < 2; ++nj_)                         \
  _Pragma("unroll") for (int kk_ = 0; kk_ < 2; ++kk_)                         \
    acc[(MI0) + mi_][(NJ0) + nj_] = __builtin_amdgcn_mfma_f32_16x16x32_bf16(  \
        aF[mi_][kk_], bF[(NJ0) + nj_][kk_], acc[(MI0) + mi_][(NJ0) + nj_],    \
        0, 0, 0);

#define GEMM8P_SYNC_PRE()                              \
  __builtin_amdgcn_s_barrier();                        \
  asm volatile("s_waitcnt lgkmcnt(0)" ::: "memory");   \
  __builtin_amdgcn_sched_barrier(0);                   \
  __builtin_amdgcn_s_setprio(1);

#define GEMM8P_SYNC_POST()                             \
  __builtin_amdgcn_s_setprio(0);                       \
  __builtin_amdgcn_s_barrier();

__global__ __launch_bounds__(512, 2) void gemm8p(
    const ushort* __restrict__ A, const ushort* __restrict__ Bt,
    const float* __restrict__ bias, ushort* __restrict__ Cout,
    int K, int ldc, int nblk_n) {
  __shared__ __align__(16) char ldsc[131072];   // [2 buf][A 32K | B 32K]

  const int nwg = gridDim.x;
  const int bid = blockIdx.x;
  const int swz = (bid & 7) * (nwg >> 3) + (bid >> 3);
  const int blockM = (swz / nblk_n) * 256;
  const int blockN = (swz % nblk_n) * 256;

  const int tid = threadIdx.x;
  const int wave = tid >> 6;
  const int lane = tid & 63;
  const int l15 = lane & 15;
  const int q = lane >> 4;
  const int wm = (wave >> 2) * 128;
  const int wn = (wave & 3) * 64;
  const int nt = K >> 6;

  f32x4 acc[8][4] = {};

  auto stage = [&](int ts, int h) {
    if (ts >= nt) return;
    char* base = ldsc + ((ts & 1) << 16) + (h << 14);
#pragma unroll
    for (int j = 0; j < 2; ++j) {
      const int idx = wave * 64 + j * 512 + lane;
      const int row = idx >> 3;
      const int cs = (idx & 7) ^ (row & 7);
      const ushort* gp =
          (h < 2 ? A + (long)(blockM + ((h & 1) << 7) + row) * K
                 : Bt + (long)(blockN + ((h & 1) << 7) + row) * K)
          + (ts << 6) + cs * 8;
      gload_lds16(gp, base + ((wave * 64 + j * 512) << 4));
    }
  };
  auto dsA = [&](int cb, int mi, int kk) {
    const int r = wm + mi * 16 + l15;
    const int cs = (kk * 4 + q) ^ (r & 7);
    return *(const bf16x8*)(ldsc + (cb << 16) + r * 128 + cs * 16);
  };
  auto dsB = [&](int cb, int nj, int kk) {
    const int r = wn + nj * 16 + l15;
    const int cs = (kk * 4 + q) ^ (r & 7);
    return *(const bf16x8*)(ldsc + (cb << 16) + 32768 + r * 128 + cs * 16);
  };

  stage(0, 0); stage(0, 1); stage(0, 2); stage(0, 3);
  stage(1, 0);
  asm volatile("s_waitcnt vmcnt(2)" ::: "memory");
  __builtin_amdgcn_s_barrier();

  bf16x8 aF[4][2], bF[4][2];
#pragma unroll 1
  for (int t = 0; t < nt; ++t) {
    const int cb = t & 1;
#pragma unroll
    for (int mi = 0; mi < 4; ++mi)
#pragma unroll
      for (int kk = 0; kk < 2; ++kk) aF[mi][kk] = dsA(cb, mi, kk);
#pragma unroll
    for (int nj = 0; nj < 2; ++nj)
#pragma unroll
      for (int kk = 0; kk < 2; ++kk) bF[nj][kk] = dsB(cb, nj, kk);
    stage(t + 1, 1);
    GEMM8P_SYNC_PRE();
    GEMM8P_QUAD(0, 0);
    GEMM8P_SYNC_POST();
#pragma unroll
    for (int nj = 2; nj < 4; ++nj)
#pragma unroll
      for (int kk = 0; kk < 2; ++kk) bF[nj][kk] = dsB(cb, nj, kk);
    stage(t + 1, 2);
    GEMM8P_SYNC_PRE();
    GEMM8P_QUAD(0, 2);
    GEMM8P_SYNC_POST();
#pragma unroll
    for (int mi = 0; mi < 4; ++mi)
#pragma unroll
      for (int kk = 0; kk < 2; ++kk) aF[mi][kk] = dsA(cb, 4 + mi, kk);
    stage(t + 1, 3);
    GEMM8P_SYNC_PRE();
    GEMM8P_QUAD(4, 2);
    GEMM8P_SYNC_POST();
    stage(t + 2, 0);
    if (t + 2 < nt) { asm volatile("s_waitcnt vmcnt(2)" ::: "memory"); }
    else            { asm volatile("s_waitcnt vmcnt(0)" ::: "memory"); }
    __builtin_amdgcn_s_barrier();
    __builtin_amdgcn_s_setprio(1);
    GEMM8P_QUAD(4, 0);
    GEMM8P_SYNC_POST();
  }

#pragma unroll
  for (int mi = 0; mi < 8; ++mi) {
#pragma unroll
    for (int nj = 0; nj < 4; ++nj) {
      const int col = blockN + wn + nj * 16 + l15;
      const float bv = bias[col];
#pragma unroll
      for (int r = 0; r < 4; ++r) {
        const int row = blockM + wm + mi * 16 + q * 4 + r;
        float v = acc[mi][nj][r] + bv;
        v = fmaxf(v, 0.0f);
        Cout[(long)row * ldc + col] = f2bf(v);
      }
    }
  }
}

// ---------------------------------------------------------------------------
// ADMM via MFMA — ROUND-10 REVERT to the round-0 kernel (best measured:
// 55.4 µs vs 61.2-103.9 for all nine rewrite attempts).
// 16 batch rows per wave; W-state kept as 3 C-layout fragments. Per iter:
//   u = 2*clip(W)-W (elementwise, C-layout); C->A relayout of u via
//   intra-wave LDS transpose (no barrier needed); W' = [base + (W-Z)] +
//   U*T^T via 18 MFMAs (hi/lo bf16 split x 2 K-chunks x 3 N-tiles),
//   T fragments register-resident.
// Post-mortem of rewrites: K16 register-feedback = slow MFMA (r2-4);
// packed-LDS/permuted-register variants = conflict/occupancy/ILP losses
// (r5-9). The r0 LDS f32 transpose is 2-way-aliased (free per m136) and
// its 4 waves/CU phase-decorrelate naturally.
// ---------------------------------------------------------------------------
__global__ __launch_bounds__(256) void admm_mfma(
    const float* raw,
    const ushort* __restrict__ Th, const ushort* __restrict__ Tl,
    const ushort* __restrict__ T0h, const ushort* __restrict__ T0l,
    const float* __restrict__ blp, const float* __restrict__ bup,
    float* outp) {
  __shared__ __align__(16) float Ubuf[4][16][68];
  const int tid = threadIdx.x, wave = tid >> 6, lane = tid & 63;
  const int l15 = lane & 15, q = lane >> 4;
  const long rowbase = (long)blockIdx.x * 64 + wave * 16;
  float (*U)[68] = Ubuf[wave];

  // zero K-pad region (cols 48..63) once; never written again
  for (int idx = lane; idx < 256; idx += 64)
    U[idx >> 4][48 + (idx & 15)] = 0.0f;

  float bl[3], bu[3];
#pragma unroll
  for (int t = 0; t < 3; ++t) { bl[t] = blp[16 * t + l15]; bu[t] = bup[16 * t + l15]; }

  // ---- peel: base = W_1 = T0 * q ------------------------------------------
  f32x4 W[3], base[3];
  {
    bf16x8 t0h[3], t0l[3];
#pragma unroll
    for (int t = 0; t < 3; ++t) {
      t0h[t] = *(const bf16x8*)(T0h + (16 * t + l15) * 32 + q * 8);
      t0l[t] = *(const bf16x8*)(T0l + (16 * t + l15) * 32 + q * 8);
    }
    float qa[8];
    if (q < 3) {
      const float* rp = raw + (rowbase + l15) * 24 + q * 8;
      float4 v0 = *(const float4*)rp;
      float4 v1 = *(const float4*)(rp + 4);
      qa[0] = v0.x; qa[1] = v0.y; qa[2] = v0.z; qa[3] = v0.w;
      qa[4] = v1.x; qa[5] = v1.y; qa[6] = v1.z; qa[7] = v1.w;
    } else {
#pragma unroll
      for (int j = 0; j < 8; ++j) qa[j] = 0.0f;
    }
    bf16x8 qhi, qlo;
    splitPack(qa, qhi, qlo);
#pragma unroll
    for (int t = 0; t < 3; ++t) {
      f32x4 acc = {0.0f, 0.0f, 0.0f, 0.0f};
      acc = __builtin_amdgcn_mfma_f32_16x16x32_bf16(qhi, t0h[t], acc, 0, 0, 0);
      acc = __builtin_amdgcn_mfma_f32_16x16x32_bf16(qlo, t0h[t], acc, 0, 0, 0);
      acc = __builtin_amdgcn_mfma_f32_16x16x32_bf16(qhi, t0l[t], acc, 0, 0, 0);
      base[t] = acc; W[t] = acc;
    }
  }

  // ---- T B-fragments (register-resident, shared layout) -------------------
  bf16x8 tbh[2][3], tbl[2][3];
#pragma unroll
  for (int c = 0; c < 2; ++c)
#pragma unroll
    for (int t = 0; t < 3; ++t) {
      tbh[c][t] = *(const bf16x8*)(Th + (16 * t + l15) * 64 + 32 * c + q * 8);
      tbl[c][t] = *(const bf16x8*)(Tl + (16 * t + l15) * 64 + 32 * c + q * 8);
    }

  float yb0[4], yb1[4];
#pragma unroll 1
  for (int it = 1; it < ADMM_ITERS; ++it) {
    f32x4 C[3];
#pragma unroll
    for (int t = 0; t < 3; ++t) {
#pragma unroll
      for (int r = 0; r < 4; ++r) {
        float w = W[t][r];
        float z = fminf(fmaxf(w, bl[t]), bu[t]);
        float u = 2.0f * z - w;
        float y = w - z;
        C[t][r] = base[t][r] + y;
        if (t == 0) yb0[r] = y;
        if (t == 1) yb1[r] = y;
        U[q * 4 + r][16 * t + l15] = u;
      }
    }
    bf16x8 uh[2], ul[2];
#pragma unroll
    for (int c = 0; c < 2; ++c) {
      const float* up = &U[l15][32 * c + q * 8];
      float4 a0 = *(const float4*)up;
      float4 a1 = *(const float4*)(up + 4);
      float ua[8] = {a0.x, a0.y, a0.z, a0.w, a1.x, a1.y, a1.z, a1.w};
      splitPack(ua, uh[c], ul[c]);
    }
#pragma unroll
    for (int t = 0; t < 3; ++t) {
      f32x4 acc = C[t];
#pragma unroll
      for (int c = 0; c < 2; ++c) {
        acc = __builtin_amdgcn_mfma_f32_16x16x32_bf16(uh[c], tbh[c][t], acc, 0, 0, 0);
        acc = __builtin_amdgcn_mfma_f32_16x16x32_bf16(ul[c], tbh[c][t], acc, 0, 0, 0);
        acc = __builtin_amdgcn_mfma_f32_16x16x32_bf16(uh[c], tbl[c][t], acc, 0, 0, 0);
      }
      W[t] = acc;
    }
  }

  // X_100 = W_100,b - (W_99 - Z_99)_b ; store cols 0..23
#pragma unroll
  for (int r = 0; r < 4; ++r) {
    const long row = rowbase + q * 4 + r;
    outp[row * 24 + l15] = W[0][r] - yb0[r];
    if (l15 < 8) outp[row * 24 + 16 + l15] = W[1][r] - yb1[r];
  }
}

// ---------------------------------------------------------------------------
extern "C" void kernel_launch(void* const* d_in, const int* in_sizes, int n_in,
                              void* d_out, int out_size, void* d_ws, size_t ws_size,
                              hipStream_t stream) {
  const float* state = (const float*)d_in[0];
  const float* Aeq   = (const float*)d_in[1];
  const float* beq   = (const float*)d_in[2];
  const float* Ain   = (const float*)d_in[3];
  const float* bin   = (const float*)d_in[4];
  const float* ub    = (const float*)d_in[5];
  const float* lb    = (const float*)d_in[6];
  const float* W1    = (const float*)d_in[7];
  const float* b1    = (const float*)d_in[8];
  const float* W2    = (const float*)d_in[9];
  const float* b2    = (const float*)d_in[10];
  const float* W3    = (const float*)d_in[11];
  const float* b3    = (const float*)d_in[12];

  const int Bn = in_sizes[0] / 512;            // 16384
  char* ws = (char*)d_ws;
  ushort* stateB = (ushort*)(ws + 0);          // 16384x512 bf16  (16 MB)
  ushort* W1T    = (ushort*)(ws + 16777216);   // 1024x512        (1 MB)
  ushort* W2T    = (ushort*)(ws + 17825792);   // 1024x1024       (2 MB)
  ushort* W3T    = (ushort*)(ws + 19922944);   // 32x1024 (rows>=24 zero)
  ushort* Th     = (ushort*)(ws + 19993600);   // 48x64 bf16 hi
  ushort* Tl     = (ushort*)(ws + 19999744);   // 48x64 bf16 lo
  ushort* T0h    = (ushort*)(ws + 20005888);   // 48x32 bf16 hi
  ushort* T0l    = (ushort*)(ws + 20008960);   // 48x32 bf16 lo
  float*  blp    = (float*) (ws + 20012032);   // 48
  float*  bup    = (float*) (ws + 20012224);   // 48
  ushort* H1     = (ushort*)(ws + 21565440);   // 16384x1024 bf16 (32 MB)
  ushort* H2     = (ushort*)(ws + 55119872);   // 16384x1024 bf16 (32 MB)
  float*  rawb   = (float*)d_out;              // gemm3 out = admm in (in-place)

  const int n4 = (Bn * 512) / 4;
  const int nConv = n4 / 256;                  // 8192
  const int nPrep = nConv + 512 + 1024 + 32 + 1;
  prep_all<<<nPrep, 256, 0, stream>>>(state, stateB, n4, W1, W1T, W2, W2T, W3, W3T,
                                      Aeq, beq, Ain, bin, ub, lb,
                                      Th, Tl, T0h, T0l, blp, bup);

  const int nblkN = 1024 / 256;                // 4
  const int nwg = (Bn / 256) * nblkN;          // 256 (div by 8 -> swizzle ok)
  gemm8p<<<nwg, 512, 0, stream>>>(stateB, W1T, b1, H1, 512, 1024, nblkN);
  gemm8p<<<nwg, 512, 0, stream>>>(H1, W2T, b2, H2, 1024, 1024, nblkN);
  gemm_bt<64, 32, 4, 1, 1, 2, 1><<<dim3(1, Bn / 64), 256, 0, stream>>>(
      H2, W3T, b3, rawb, 1024, 24, 24);

  admm_mfma<<<Bn / 64, 256, 0, stream>>>(rawb, Th, Tl, T0h, T0l, blp, bup,
                                         (float*)d_out);
}